// Round 3
// baseline (3041.952 us; speedup 1.0000x reference)
//
#include <hip/hip_runtime.h>
#include <math.h>

#define B_ 128
#define S_ 128
#define T_ 127
#define D_ 100
#define QN_ 4
#define SN_ 4
#define KC_ 4
#define RK_ 10
#define NEGV -1000000000.0f

__device__ __forceinline__ float sigmf(float x) { return 1.0f / (1.0f + expf(-x)); }

// ---------------------------------------------------------------------------
// Setup: transposed copies of W_ih1a, Wagg, W_last, W_key, W_query for
// coalesced matvecs; fold Er@W_ih1b + b_ih1 into erw; scalars.
// ---------------------------------------------------------------------------
__global__ __launch_bounds__(256) void setupk(
    const float* Er, const float* W_ih1, const float* b_ih1,
    const float* Wagg, const float* W_last, const float* W_key, const float* W_query,
    const float* b_query, const float* W_W,
    float* wih1aT, float* erw, float* waggT, float* wlastT, float* wkeyT, float* wqT,
    float* scal)
{
  int gid = blockIdx.x * blockDim.x + threadIdx.x;
  int gsz = gridDim.x * blockDim.x;

  // W_ih1[:, :100] transposed: wih1aT[j*300+i] = W_ih1[i][j]
  for (int x = gid; x < 30000; x += gsz) {
    int j = x / 300, i = x % 300;
    wih1aT[j * 300 + i] = W_ih1[i * 200 + j];
  }
  // erw[r][i] = b_ih1[i] + sum_j Er[r][j]*W_ih1[i][100+j]
  for (int x = gid; x < 600; x += gsz) {
    int r = x / 300, i = x % 300;
    float acc = b_ih1[i];
    for (int j = 0; j < 100; j++) acc += Er[r * 100 + j] * W_ih1[i * 200 + 100 + j];
    erw[x] = acc;
  }
  // Wagg transposed per hop
  for (int x = gid; x < 30000; x += gsz) {
    int h = x / 10000, rr = x % 10000, j = rr / 100, i = rr % 100;
    waggT[h * 10000 + j * 100 + i] = Wagg[h * 10000 + i * 100 + j];
  }
  for (int x = gid; x < 10000; x += gsz) {
    int j = x / 100, i = x % 100;
    wlastT[j * 100 + i] = W_last[i * 100 + j];
    wkeyT[j * 100 + i] = W_key[i * 100 + j];
    wqT[j * 100 + i] = W_query[i * 100 + j];
  }
  if (gid == 0) {
    float acc = 0.f;  // kw of the all-zero hist state: dot(tanh(b_query), Wk_part)
    for (int i = 0; i < 100; i++) acc += tanhf(b_query[i]) * W_W[100 + i];
    scal[0] = acc;
  }
}

// ---------------------------------------------------------------------------
// Phase A: per (b,t) compute emb_q (3-hop aggregate where mask!=0, else Eq row)
// and produce gi1[b,t,0:300] = emb_q@W_ih1a^T + (Er[r]@W_ih1b^T + b_ih1)
// ---------------------------------------------------------------------------
__global__ __launch_bounds__(256) void phaseA(
    const float* Eq, const float* Ec, const int* question, const int* response, const int* mask,
    const int* qnb, const int* snb,
    const float* wih1aT, const float* erw, const float* waggT, const float* wlastT,
    const float* baggf, const float* blastf, float* gi1_all)
{
  const int t = blockIdx.x, b = blockIdx.y, tid = threadIdx.x;
  __shared__ float e0[100], ne0[100], e1[400], ne1[400];
  __shared__ float e2[1600], ne2[1600], m3[1600];
  __shared__ float sum4[400], sum1[100], emq[100];
  __shared__ int l1[4], l2[16], l3[64];

  const int qt = question[b * S_ + t];
  const int mt = mask[b * S_ + t];
  const int rt = response[b * S_ + t];

  if (mt != 0) {
    if (tid < 4) l1[tid] = qnb[qt * QN_ + tid];
    for (int x = tid; x < 100; x += 256) e0[x] = Eq[(size_t)qt * 100 + x];
    __syncthreads();
    if (tid < 16) l2[tid] = snb[l1[tid >> 2] * SN_ + (tid & 3)];
    for (int x = tid; x < 400; x += 256) e1[x] = Ec[(size_t)l1[x / 100] * 100 + (x % 100)];
    __syncthreads();
    if (tid < 64) l3[tid] = qnb[l2[tid >> 2] * QN_ + (tid & 3)];
    for (int x = tid; x < 1600; x += 256) e2[x] = Eq[(size_t)l2[x / 100] * 100 + (x % 100)];
    __syncthreads();
    // hop-0 inputs (all from OLD values): m3 = e2 + mean(level3 Ec rows);
    // sum4 = e1 + mean(e2 groups); sum1 = e0 + mean(e1)
    for (int x = tid; x < 1600; x += 256) {
      int r = x / 100, j = x % 100;
      const int* lr = l3 + r * 4;
      float s = Ec[(size_t)lr[0] * 100 + j] + Ec[(size_t)lr[1] * 100 + j] +
                Ec[(size_t)lr[2] * 100 + j] + Ec[(size_t)lr[3] * 100 + j];
      m3[x] = e2[x] + 0.25f * s;
    }
    for (int x = tid; x < 100; x += 256)
      sum1[x] = e0[x] + 0.25f * (e1[x] + e1[100 + x] + e1[200 + x] + e1[300 + x]);
    for (int x = tid; x < 400; x += 256) {
      int k = x / 100, j = x % 100;
      const float* e2k = e2 + k * 400;
      sum4[x] = e1[x] + 0.25f * (e2k[j] + e2k[100 + j] + e2k[200 + j] + e2k[300 + j]);
    }
    __syncthreads();
    // hop-0 matvecs: ne0(100) | ne1(400) | ne2(1600) ; Wagg index = j (0/1/2)
    for (int o = tid; o < 2100; o += 256) {
      const float *in, *W;
      float bia;
      float* dst;
      int i = o % 100;
      if (o < 100)      { in = sum1;                           W = waggT;          bia = baggf[i];       dst = ne0 + o; }
      else if (o < 500) { in = sum4 + ((o - 100) / 100) * 100; W = waggT + 10000;  bia = baggf[100 + i]; dst = ne1 + (o - 100); }
      else              { in = m3 + ((o - 500) / 100) * 100;   W = waggT + 20000;  bia = baggf[200 + i]; dst = ne2 + (o - 500); }
      float acc = bia;
      for (int j = 0; j < 100; j++) acc += in[j] * W[j * 100 + i];
      *dst = tanhf(acc);
    }
    __syncthreads();
    // hop-1 inputs
    for (int x = tid; x < 100; x += 256)
      sum1[x] = ne0[x] + 0.25f * (ne1[x] + ne1[100 + x] + ne1[200 + x] + ne1[300 + x]);
    for (int x = tid; x < 400; x += 256) {
      int k = x / 100, j = x % 100;
      const float* n2k = ne2 + k * 400;
      sum4[x] = ne1[x] + 0.25f * (n2k[j] + n2k[100 + j] + n2k[200 + j] + n2k[300 + j]);
    }
    __syncthreads();
    // hop-1 matvecs -> e0(100), e1(400)
    for (int o = tid; o < 500; o += 256) {
      int i = o % 100;
      if (o < 100) {
        float acc = baggf[i];
        for (int j = 0; j < 100; j++) acc += sum1[j] * waggT[j * 100 + i];
        e0[i] = tanhf(acc);
      } else {
        const float* in = sum4 + ((o - 100) / 100) * 100;
        float acc = baggf[100 + i];
        for (int j = 0; j < 100; j++) acc += in[j] * waggT[10000 + j * 100 + i];
        e1[o - 100] = tanhf(acc);
      }
    }
    __syncthreads();
    // hop-2
    for (int x = tid; x < 100; x += 256)
      sum1[x] = e0[x] + 0.25f * (e1[x] + e1[100 + x] + e1[200 + x] + e1[300 + x]);
    __syncthreads();
    for (int o = tid; o < 100; o += 256) {
      float acc = baggf[o];
      for (int j = 0; j < 100; j++) acc += sum1[j] * waggT[j * 100 + o];
      ne0[o] = tanhf(acc);
    }
    __syncthreads();
    // final W_last
    for (int o = tid; o < 100; o += 256) {
      float acc = blastf[o];
      for (int j = 0; j < 100; j++) acc += ne0[j] * wlastT[j * 100 + o];
      emq[o] = tanhf(acc);
    }
    __syncthreads();
  } else {
    for (int x = tid; x < 100; x += 256) emq[x] = Eq[(size_t)qt * 100 + x];
    __syncthreads();
  }

  const size_t bt = (size_t)b * T_ + t;
  for (int o = tid; o < 300; o += 256) {
    float acc = erw[rt * 300 + o];
    for (int j = 0; j < 100; j++) acc += emq[j] * wih1aT[j * 300 + o];
    gi1_all[bt * 300 + o] = acc;
  }
}

// ---------------------------------------------------------------------------
// Phase B: per (b,t): qw[5] = tanh(qc@W_key^T+b_key)·Wq_part, and (t>RK) the
// top-10 indices of scores[s]=Eq[q_s]·Eq[q_next] masked to s<t.
// Tie-break: larger value then smaller index (matches lax.top_k selection set).
// ---------------------------------------------------------------------------
__global__ __launch_bounds__(128) void phaseB(
    const float* Eq, const float* Ec, const int* question, const int* cidx, const int* cmask,
    const float* wkeyT, const float* b_key, const float* W_W,
    float* qw_all, int* top10_all)
{
  const int t = blockIdx.x, b = blockIdx.y, tid = threadIdx.x;
  const size_t bt = (size_t)b * T_ + t;
  __shared__ float qcf[500];
  __shared__ float qtl[500];
  __shared__ float qwp[20];
  __shared__ float orig[128];
  __shared__ float sval[128];
  __shared__ int sidx[128];
  __shared__ int ci[4], cm[4];

  const int qn = question[b * S_ + t + 1];
  if (tid < 4) { ci[tid] = cidx[qn * KC_ + tid]; cm[tid] = cmask[qn * KC_ + tid]; }
  __syncthreads();

  for (int u = tid; u < 500; u += 128) {
    int row = u / 100, j = u % 100;
    float v;
    if (row == 0) v = Eq[(size_t)qn * 100 + j];
    else {
      int k = row - 1;
      v = cm[k] ? Ec[(size_t)ci[k] * 100 + j] : 0.f;
    }
    qcf[u] = v;
  }
  __syncthreads();
  for (int o = tid; o < 500; o += 128) {
    int q = o / 100, i = o % 100;
    float acc = b_key[i];
    const float* src = qcf + q * 100;
    for (int j = 0; j < 100; j++) acc += src[j] * wkeyT[j * 100 + i];
    qtl[o] = tanhf(acc);
  }
  __syncthreads();
  if (tid < 20) {
    int q = tid / 4, part = tid % 4;
    float acc = 0.f;
    for (int j = part * 25; j < part * 25 + 25; j++) acc += qtl[q * 100 + j] * W_W[j];
    qwp[tid] = acc;
  }
  __syncthreads();
  if (tid < 5) qw_all[bt * 5 + tid] = qwp[tid * 4] + qwp[tid * 4 + 1] + qwp[tid * 4 + 2] + qwp[tid * 4 + 3];

  if (t > RK_) {
    float sc = -__builtin_inff();
    if (tid < t) {
      int qs = question[b * S_ + tid];
      float acc = 0.f;
      for (int j = 0; j < 100; j++) acc += Eq[(size_t)qs * 100 + j] * qcf[j];
      sc = acc;
    }
    orig[tid] = sc;
    __syncthreads();
    for (int pass = 0; pass < 10; pass++) {
      sval[tid] = orig[tid];
      sidx[tid] = tid;
      __syncthreads();
      for (int offt = 64; offt > 0; offt >>= 1) {
        if (tid < offt) {
          float v2 = sval[tid + offt];
          int i2 = sidx[tid + offt];
          if (v2 > sval[tid] || (v2 == sval[tid] && i2 < sidx[tid])) { sval[tid] = v2; sidx[tid] = i2; }
        }
        __syncthreads();
      }
      if (tid == 0) top10_all[bt * 10 + pass] = sidx[0];
      if (tid == sidx[0]) orig[tid] = -__builtin_inff();
      __syncthreads();
    }
  }
}

// ---------------------------------------------------------------------------
// Sequential scan: one workgroup per batch row. W_hh1||W_hh2 rows and W_ih2
// half-rows in per-thread REGISTERS (loaded once); g2 history in LDS (50.8KB);
// gi1 row prefetched one step ahead into LDS; qc gathered per step in LDS.
// Total LDS ~62KB. out is float32.
// ---------------------------------------------------------------------------
__global__ __launch_bounds__(640, 1) void seqk(
    const float* gi1_all, const float* W_hh1, const float* W_hh2, const float* W_ih2,
    const float* b_hh1, const float* b_hh2, const float* b_ih2, const float* b_query,
    const float* wqT, const float* W_W, const float* b_W,
    const float* qw_all, const int* top10_all,
    const float* Eq, const float* Ec, const int* question, const int* cidx, const int* cmask,
    const float* h1_init, const float* h2_init, const float* scal,
    float* out)
{
  const int b = blockIdx.x, tid = threadIdx.x;
  __shared__ float g2hs[T_ * 100];       // 50.8 KB history of g2 (row 0 = zeros)
  __shared__ float gi1buf[300];
  __shared__ float qc[500];
  __shared__ __align__(16) float h1[100], h2[100], h1n[100], g2v[100], kq[100];
  __shared__ float gh1[300], gh2[300];
  __shared__ float gi2p[2][300];
  __shared__ float kwhist[128];
  __shared__ float ogp[55][2];
  __shared__ float qwl[5];
  __shared__ float pq[5];
  __shared__ int topidx[10];
  __shared__ int qn_s, ci_s[4], cm_s[4];
  __shared__ float kwcur_s;

  // --- per-thread register weights ---
  float wr[100];   // W_hh row (tid<600)
  float wi2[50];   // W_ih2 half-row
  float bh = 0.f, bi2 = 0.f, bqv = 0.f;
  int o3 = 0, half3 = 0;
  if (tid < 600) {
    o3 = tid % 300;
    half3 = tid / 300;
    const float* src = (tid < 300) ? (W_hh1 + (size_t)tid * 100) : (W_hh2 + (size_t)(tid - 300) * 100);
#pragma unroll
    for (int k = 0; k < 100; k++) wr[k] = src[k];
#pragma unroll
    for (int k = 0; k < 50; k++) wi2[k] = W_ih2[(size_t)o3 * 100 + half3 * 50 + k];
    bh = (tid < 300) ? b_hh1[tid] : b_hh2[tid - 300];
    if (half3 == 0) bi2 = b_ih2[o3];
  }
  if (tid < 100) bqv = b_query[tid];

  const float bWv = b_W[0];
  const float kw0 = scal[0];
  if (tid < 100) {
    h1[tid] = h1_init[b * 100 + tid];
    h2[tid] = h2_init[b * 100 + tid];
    g2hs[tid] = 0.f;  // history row 0 stays zero
  }
  if (tid < 128) kwhist[tid] = kw0;
  for (int x = tid; x < 300; x += 640) gi1buf[x] = gi1_all[(size_t)b * T_ * 300 + x];  // t=0 prefetch
  __syncthreads();

  for (int t = 0; t < T_; t++) {
    const size_t bt = (size_t)b * T_ + t;
    // ---- S1: gh1/gh2 matvec from registers; aux loads ----
    if (tid < 600) {
      const float* hsrc = (tid < 300) ? h1 : h2;
      float acc = bh;
#pragma unroll
      for (int k = 0; k < 100; k += 4) {
        float4 hv = *(const float4*)&hsrc[k];
        acc += wr[k] * hv.x + wr[k + 1] * hv.y + wr[k + 2] * hv.z + wr[k + 3] * hv.w;
      }
      if (tid < 300) gh1[tid] = acc;
      else gh2[tid - 300] = acc;
    } else {
      int u = tid - 600;
      if (u < 10) {
        if (t > RK_) {
          int v = top10_all[bt * 10 + u];
          topidx[u] = min(T_ - 1, max(0, v));  // defensive clamp
        }
      } else if (u < 15) {
        qwl[u - 10] = qw_all[bt * 5 + (u - 10)];
      } else if (u == 32) {
        qn_s = question[b * S_ + t + 1];
      }
    }
    __syncthreads();
    // ---- S2: GRU1 combine; concept idx/mask loads ----
    if (tid < 100) {
      int j = tid;
      float r = sigmf(gi1buf[j] + gh1[j]);
      float z = sigmf(gi1buf[100 + j] + gh1[100 + j]);
      float n = tanhf(gi1buf[200 + j] + r * gh1[200 + j]);
      h1n[j] = (1.f - z) * n + z * h1[j];
    } else if (tid >= 104 && tid < 112) {
      int k = tid - 104;
      if (k < 4) ci_s[k] = cidx[qn_s * KC_ + k];
      else cm_s[k - 4] = cmask[qn_s * KC_ + (k - 4)];
    }
    __syncthreads();
    // ---- S3: gi2 partial matvec from registers; qc gather ----
    if (tid < 600) {
      float acc = bi2;
#pragma unroll
      for (int k = 0; k < 50; k += 2) {
        float2 hv = *(const float2*)&h1n[half3 * 50 + k];
        acc += wi2[k] * hv.x + wi2[k + 1] * hv.y;
      }
      gi2p[half3][o3] = acc;
    } else {
      for (int x = tid - 600; x < 500; x += 40) {
        int q = x / 100, j = x % 100;
        float v;
        if (q == 0) v = Eq[(size_t)qn_s * 100 + j];
        else v = cm_s[q - 1] ? Ec[(size_t)ci_s[q - 1] * 100 + j] : 0.f;
        qc[x] = v;
      }
    }
    __syncthreads();
    // ---- S4: GRU2 combine ----
    if (tid < 100) {
      int j = tid;
      float gr = gi2p[0][j] + gi2p[1][j];
      float gz = gi2p[0][100 + j] + gi2p[1][100 + j];
      float gn = gi2p[0][200 + j] + gi2p[1][200 + j];
      float r = sigmf(gr + gh2[j]);
      float z = sigmf(gz + gh2[100 + j]);
      float n = tanhf(gn + r * gh2[200 + j]);
      g2v[j] = (1.f - z) * n + z * h2[j];
    }
    __syncthreads();
    // ---- S5: kq matvec | state copies | hist write | og partials | gi1 prefetch ----
    if (tid < 100) {
      int i = tid;
      float acc = bqv;
      for (int j = 0; j < 100; j++) acc += wqT[j * 100 + i] * g2v[j];
      kq[i] = tanhf(acc);
    } else if (tid < 200) {
      h1[tid - 100] = h1n[tid - 100];
    } else if (tid < 300) {
      if (t > 0) h2[tid - 200] = g2v[tid - 200];
    } else if (tid < 400) {
      if (t > 0) g2hs[t * 100 + (tid - 300)] = g2v[tid - 300];
    } else if (tid < 510) {
      int u = tid - 400, d = u >> 1, part = u & 1;
      int s = d / 5, q = d % 5;
      const float* qcr = qc + q * 100;
      float acc = 0.f;
      int jb = part * 50;
      if (s == 0) {
#pragma unroll
        for (int j = 0; j < 50; j += 2) {
          float2 g = *(const float2*)&g2v[jb + j];
          acc += qcr[jb + j] * g.x + qcr[jb + j + 1] * g.y;
        }
      } else {
        int idx = (t > RK_) ? topidx[s - 1] : (s - 1);
        if ((t > RK_) || (s - 1 < t)) {
          const float* hr = g2hs + idx * 100;
          for (int j = 0; j < 50; j++) acc += qcr[jb + j] * hr[jb + j];
        }
      }
      ogp[d][part] = acc;
    } else if (tid >= 576) {
      if (t + 1 < T_) {
        const float* src = gi1_all + (bt + 1) * 300;
        for (int x = tid - 576; x < 300; x += 64) gi1buf[x] = src[x];
      }
    }
    __syncthreads();
    // ---- S6: kw_cur = dot(kq, Wk_part) on wave 8 ----
    if (tid >= 512 && tid < 576) {
      int lane = tid - 512;
      float v = 0.f;
      if (lane < 50) v = kq[lane] * W_W[100 + lane] + kq[lane + 50] * W_W[150 + lane];
      v += __shfl_down(v, 32);
      v += __shfl_down(v, 16);
      v += __shfl_down(v, 8);
      v += __shfl_down(v, 4);
      v += __shfl_down(v, 2);
      v += __shfl_down(v, 1);
      if (lane == 0) kwcur_s = v;
    }
    __syncthreads();
    // ---- S7: per-q softmax over 11 states ----
    if (tid < 5) {
      const int q = tid;
      const float qw = qwl[q];
      float tmp[11];
      float m = -__builtin_inff();
#pragma unroll
      for (int s = 0; s < 11; s++) {
        float kws;
        bool valid;
        if (s == 0) { kws = kwcur_s; valid = true; }
        else if (t > RK_) { kws = kwhist[topidx[s - 1]]; valid = true; }
        else { valid = (s - 1 < t); kws = kwhist[s - 1]; }
        float tv = valid ? (qw + kws + bWv) : NEGV;
        tmp[s] = tv;
        m = fmaxf(m, tv);
      }
      float den = 0.f, num = 0.f;
#pragma unroll
      for (int s = 0; s < 11; s++) {
        float e = expf(tmp[s] - m);
        den += e;
        num += e * (ogp[s * 5 + q][0] + ogp[s * 5 + q][1]);
      }
      pq[q] = num / den;
    } else if (tid == 8) {
      if (t > 0) kwhist[t] = kwcur_s;
    }
    __syncthreads();
    // ---- S8: final sum + store (f32 out) ----
    if (tid == 0) {
      float p = pq[0] + pq[1] + pq[2] + pq[3] + pq[4];
      int col = (t == 0) ? 0 : (t + 1);
      out[b * S_ + col] = p;
      if (t == 0) out[b * S_ + 1] = 0.f;  // col 1 never written by ref (yhat stays 0)
    }
    __syncthreads();
  }
}

// ---------------------------------------------------------------------------
extern "C" void kernel_launch(void* const* d_in, const int* in_sizes, int n_in,
                              void* d_out, int out_size, void* d_ws, size_t ws_size,
                              hipStream_t stream)
{
  (void)in_sizes; (void)n_in; (void)out_size; (void)ws_size;
  const float* Eq     = (const float*)d_in[0];
  const float* Ec     = (const float*)d_in[1];
  const float* Er     = (const float*)d_in[2];
  const float* W_ih1  = (const float*)d_in[3];
  const float* W_hh1  = (const float*)d_in[4];
  const float* b_ih1  = (const float*)d_in[5];
  const float* b_hh1  = (const float*)d_in[6];
  const float* W_ih2  = (const float*)d_in[7];
  const float* W_hh2  = (const float*)d_in[8];
  const float* b_ih2  = (const float*)d_in[9];
  const float* b_hh2  = (const float*)d_in[10];
  const float* Wagg   = (const float*)d_in[11];
  const float* bagg   = (const float*)d_in[12];
  const float* W_last = (const float*)d_in[13];
  const float* b_last = (const float*)d_in[14];
  const float* W_query= (const float*)d_in[15];
  const float* b_query= (const float*)d_in[16];
  const float* W_key  = (const float*)d_in[17];
  const float* b_key  = (const float*)d_in[18];
  const float* W_W    = (const float*)d_in[19];
  const float* b_W    = (const float*)d_in[20];
  const float* h1_init= (const float*)d_in[21];
  const float* h2_init= (const float*)d_in[22];
  const int* question = (const int*)d_in[23];
  const int* response = (const int*)d_in[24];
  const int* mask     = (const int*)d_in[25];
  const int* qnb      = (const int*)d_in[26];
  const int* snb      = (const int*)d_in[27];
  const int* cidx     = (const int*)d_in[28];
  const int* cmask    = (const int*)d_in[29];
  float* out = (float*)d_out;

  char* ws = (char*)d_ws;
  size_t off = 0;
  auto alloc = [&](size_t bytes) -> void* {
    void* p = ws + off;
    off += (bytes + 255) & ~(size_t)255;
    return p;
  };
  float* wih1aT = (float*)alloc(30000 * 4);
  float* erw    = (float*)alloc(600 * 4);
  float* waggT  = (float*)alloc(30000 * 4);
  float* wlastT = (float*)alloc(10000 * 4);
  float* wkeyT  = (float*)alloc(10000 * 4);
  float* wqT    = (float*)alloc(10000 * 4);
  float* scal   = (float*)alloc(4);
  float* gi1_all = (float*)alloc((size_t)B_ * T_ * 300 * 4);
  float* qw_all  = (float*)alloc((size_t)B_ * T_ * 5 * 4);
  int*   top10   = (int*)alloc((size_t)B_ * T_ * 10 * 4);

  hipLaunchKernelGGL(setupk, dim3(128), dim3(256), 0, stream,
      Er, W_ih1, b_ih1, Wagg, W_last, W_key, W_query, b_query, W_W,
      wih1aT, erw, waggT, wlastT, wkeyT, wqT, scal);

  hipLaunchKernelGGL(phaseA, dim3(T_, B_), dim3(256), 0, stream,
      Eq, Ec, question, response, mask, qnb, snb,
      wih1aT, erw, waggT, wlastT, bagg, b_last, gi1_all);

  hipLaunchKernelGGL(phaseB, dim3(T_, B_), dim3(128), 0, stream,
      Eq, Ec, question, cidx, cmask, wkeyT, b_key, W_W,
      qw_all, top10);

  hipLaunchKernelGGL(seqk, dim3(B_), dim3(640), 0, stream,
      gi1_all, W_hh1, W_hh2, W_ih2, b_hh1, b_hh2, b_ih2, b_query,
      wqT, W_W, b_W, qw_all, top10,
      Eq, Ec, question, cidx, cmask,
      h1_init, h2_init, scal, out);
}

// Round 4
// 3014.385 us; speedup vs baseline: 1.0091x; 1.0091x over previous
//
#include <hip/hip_runtime.h>
#include <math.h>

#define B_ 128
#define S_ 128
#define T_ 127
#define D_ 100
#define QN_ 4
#define SN_ 4
#define KC_ 4
#define RK_ 10
#define NEGV -1000000000.0f

__device__ __forceinline__ float sigmf(float x) { return 1.0f / (1.0f + expf(-x)); }

// ---------------------------------------------------------------------------
// Setup: transposed copies of W_ih1a, Wagg, W_last, W_key, W_query for
// coalesced matvecs; fold Er@W_ih1b + b_ih1 into erw; scalars.
// ---------------------------------------------------------------------------
__global__ __launch_bounds__(256) void setupk(
    const float* Er, const float* W_ih1, const float* b_ih1,
    const float* Wagg, const float* W_last, const float* W_key, const float* W_query,
    const float* b_query, const float* W_W,
    float* wih1aT, float* erw, float* waggT, float* wlastT, float* wkeyT, float* wqT,
    float* scal)
{
  int gid = blockIdx.x * blockDim.x + threadIdx.x;
  int gsz = gridDim.x * blockDim.x;

  // W_ih1[:, :100] transposed: wih1aT[j*300+i] = W_ih1[i][j]
  for (int x = gid; x < 30000; x += gsz) {
    int j = x / 300, i = x % 300;
    wih1aT[j * 300 + i] = W_ih1[i * 200 + j];
  }
  // erw[r][i] = b_ih1[i] + sum_j Er[r][j]*W_ih1[i][100+j]
  for (int x = gid; x < 600; x += gsz) {
    int r = x / 300, i = x % 300;
    float acc = b_ih1[i];
    for (int j = 0; j < 100; j++) acc += Er[r * 100 + j] * W_ih1[i * 200 + 100 + j];
    erw[x] = acc;
  }
  // Wagg transposed per hop
  for (int x = gid; x < 30000; x += gsz) {
    int h = x / 10000, rr = x % 10000, j = rr / 100, i = rr % 100;
    waggT[h * 10000 + j * 100 + i] = Wagg[h * 10000 + i * 100 + j];
  }
  for (int x = gid; x < 10000; x += gsz) {
    int j = x / 100, i = x % 100;
    wlastT[j * 100 + i] = W_last[i * 100 + j];
    wkeyT[j * 100 + i] = W_key[i * 100 + j];
    wqT[j * 100 + i] = W_query[i * 100 + j];
  }
  if (gid == 0) {
    float acc = 0.f;  // kw of the all-zero hist state: dot(tanh(b_query), Wk_part)
    for (int i = 0; i < 100; i++) acc += tanhf(b_query[i]) * W_W[100 + i];
    scal[0] = acc;
  }
}

// ---------------------------------------------------------------------------
// Phase A: per (b,t) compute emb_q (3-hop aggregate where mask!=0, else Eq row)
// and produce gi1[b,t,0:300] = emb_q@W_ih1a^T + (Er[r]@W_ih1b^T + b_ih1)
// ---------------------------------------------------------------------------
__global__ __launch_bounds__(256) void phaseA(
    const float* Eq, const float* Ec, const int* question, const int* response, const int* mask,
    const int* qnb, const int* snb,
    const float* wih1aT, const float* erw, const float* waggT, const float* wlastT,
    const float* baggf, const float* blastf, float* gi1_all)
{
  const int t = blockIdx.x, b = blockIdx.y, tid = threadIdx.x;
  __shared__ float e0[100], ne0[100], e1[400], ne1[400];
  __shared__ float e2[1600], ne2[1600], m3[1600];
  __shared__ float sum4[400], sum1[100], emq[100];
  __shared__ int l1[4], l2[16], l3[64];

  const int qt = question[b * S_ + t];
  const int mt = mask[b * S_ + t];
  const int rt = response[b * S_ + t];

  if (mt != 0) {
    if (tid < 4) l1[tid] = qnb[qt * QN_ + tid];
    for (int x = tid; x < 100; x += 256) e0[x] = Eq[(size_t)qt * 100 + x];
    __syncthreads();
    if (tid < 16) l2[tid] = snb[l1[tid >> 2] * SN_ + (tid & 3)];
    for (int x = tid; x < 400; x += 256) e1[x] = Ec[(size_t)l1[x / 100] * 100 + (x % 100)];
    __syncthreads();
    if (tid < 64) l3[tid] = qnb[l2[tid >> 2] * QN_ + (tid & 3)];
    for (int x = tid; x < 1600; x += 256) e2[x] = Eq[(size_t)l2[x / 100] * 100 + (x % 100)];
    __syncthreads();
    // hop-0 inputs: m3 = e2 + mean(level3 Ec rows); sum4 = e1 + mean(e2); sum1 = e0 + mean(e1)
    for (int x = tid; x < 1600; x += 256) {
      int r = x / 100, j = x % 100;
      const int* lr = l3 + r * 4;
      float s = Ec[(size_t)lr[0] * 100 + j] + Ec[(size_t)lr[1] * 100 + j] +
                Ec[(size_t)lr[2] * 100 + j] + Ec[(size_t)lr[3] * 100 + j];
      m3[x] = e2[x] + 0.25f * s;
    }
    for (int x = tid; x < 100; x += 256)
      sum1[x] = e0[x] + 0.25f * (e1[x] + e1[100 + x] + e1[200 + x] + e1[300 + x]);
    for (int x = tid; x < 400; x += 256) {
      int k = x / 100, j = x % 100;
      const float* e2k = e2 + k * 400;
      sum4[x] = e1[x] + 0.25f * (e2k[j] + e2k[100 + j] + e2k[200 + j] + e2k[300 + j]);
    }
    __syncthreads();
    // hop-0 matvecs: ne0(100) | ne1(400) | ne2(1600)
    for (int o = tid; o < 2100; o += 256) {
      const float *in, *W;
      float bia;
      float* dst;
      int i = o % 100;
      if (o < 100)      { in = sum1;                           W = waggT;          bia = baggf[i];       dst = ne0 + o; }
      else if (o < 500) { in = sum4 + ((o - 100) / 100) * 100; W = waggT + 10000;  bia = baggf[100 + i]; dst = ne1 + (o - 100); }
      else              { in = m3 + ((o - 500) / 100) * 100;   W = waggT + 20000;  bia = baggf[200 + i]; dst = ne2 + (o - 500); }
      float acc = bia;
      for (int j = 0; j < 100; j++) acc += in[j] * W[j * 100 + i];
      *dst = tanhf(acc);
    }
    __syncthreads();
    // hop-1 inputs
    for (int x = tid; x < 100; x += 256)
      sum1[x] = ne0[x] + 0.25f * (ne1[x] + ne1[100 + x] + ne1[200 + x] + ne1[300 + x]);
    for (int x = tid; x < 400; x += 256) {
      int k = x / 100, j = x % 100;
      const float* n2k = ne2 + k * 400;
      sum4[x] = ne1[x] + 0.25f * (n2k[j] + n2k[100 + j] + n2k[200 + j] + n2k[300 + j]);
    }
    __syncthreads();
    // hop-1 matvecs -> e0(100), e1(400)
    for (int o = tid; o < 500; o += 256) {
      int i = o % 100;
      if (o < 100) {
        float acc = baggf[i];
        for (int j = 0; j < 100; j++) acc += sum1[j] * waggT[j * 100 + i];
        e0[i] = tanhf(acc);
      } else {
        const float* in = sum4 + ((o - 100) / 100) * 100;
        float acc = baggf[100 + i];
        for (int j = 0; j < 100; j++) acc += in[j] * waggT[10000 + j * 100 + i];
        e1[o - 100] = tanhf(acc);
      }
    }
    __syncthreads();
    // hop-2
    for (int x = tid; x < 100; x += 256)
      sum1[x] = e0[x] + 0.25f * (e1[x] + e1[100 + x] + e1[200 + x] + e1[300 + x]);
    __syncthreads();
    for (int o = tid; o < 100; o += 256) {
      float acc = baggf[o];
      for (int j = 0; j < 100; j++) acc += sum1[j] * waggT[j * 100 + o];
      ne0[o] = tanhf(acc);
    }
    __syncthreads();
    // final W_last
    for (int o = tid; o < 100; o += 256) {
      float acc = blastf[o];
      for (int j = 0; j < 100; j++) acc += ne0[j] * wlastT[j * 100 + o];
      emq[o] = tanhf(acc);
    }
    __syncthreads();
  } else {
    for (int x = tid; x < 100; x += 256) emq[x] = Eq[(size_t)qt * 100 + x];
    __syncthreads();
  }

  const size_t bt = (size_t)b * T_ + t;
  for (int o = tid; o < 300; o += 256) {
    float acc = erw[rt * 300 + o];
    for (int j = 0; j < 100; j++) acc += emq[j] * wih1aT[j * 300 + o];
    gi1_all[bt * 300 + o] = acc;
  }
}

// ---------------------------------------------------------------------------
// Phase B: per (b,t): qw[5] = tanh(qc@W_key^T+b_key)·Wq_part, and (t>RK) the
// top-10 indices of scores[s]=Eq[q_s]·Eq[q_next] masked to s<t.
// Tie-break: larger value then smaller index (matches lax.top_k selection set).
// ---------------------------------------------------------------------------
__global__ __launch_bounds__(128) void phaseB(
    const float* Eq, const float* Ec, const int* question, const int* cidx, const int* cmask,
    const float* wkeyT, const float* b_key, const float* W_W,
    float* qw_all, int* top10_all)
{
  const int t = blockIdx.x, b = blockIdx.y, tid = threadIdx.x;
  const size_t bt = (size_t)b * T_ + t;
  __shared__ float qcf[500];
  __shared__ float qtl[500];
  __shared__ float qwp[20];
  __shared__ float orig[128];
  __shared__ float sval[128];
  __shared__ int sidx[128];
  __shared__ int ci[4], cm[4];

  const int qn = question[b * S_ + t + 1];
  if (tid < 4) { ci[tid] = cidx[qn * KC_ + tid]; cm[tid] = cmask[qn * KC_ + tid]; }
  __syncthreads();

  for (int u = tid; u < 500; u += 128) {
    int row = u / 100, j = u % 100;
    float v;
    if (row == 0) v = Eq[(size_t)qn * 100 + j];
    else {
      int k = row - 1;
      v = cm[k] ? Ec[(size_t)ci[k] * 100 + j] : 0.f;
    }
    qcf[u] = v;
  }
  __syncthreads();
  for (int o = tid; o < 500; o += 128) {
    int q = o / 100, i = o % 100;
    float acc = b_key[i];
    const float* src = qcf + q * 100;
    for (int j = 0; j < 100; j++) acc += src[j] * wkeyT[j * 100 + i];
    qtl[o] = tanhf(acc);
  }
  __syncthreads();
  if (tid < 20) {
    int q = tid / 4, part = tid % 4;
    float acc = 0.f;
    for (int j = part * 25; j < part * 25 + 25; j++) acc += qtl[q * 100 + j] * W_W[j];
    qwp[tid] = acc;
  }
  __syncthreads();
  if (tid < 5) qw_all[bt * 5 + tid] = qwp[tid * 4] + qwp[tid * 4 + 1] + qwp[tid * 4 + 2] + qwp[tid * 4 + 3];

  if (t > RK_) {
    float sc = -__builtin_inff();
    if (tid < t) {
      int qs = question[b * S_ + tid];
      float acc = 0.f;
      for (int j = 0; j < 100; j++) acc += Eq[(size_t)qs * 100 + j] * qcf[j];
      sc = acc;
    }
    orig[tid] = sc;
    __syncthreads();
    for (int pass = 0; pass < 10; pass++) {
      sval[tid] = orig[tid];
      sidx[tid] = tid;
      __syncthreads();
      for (int offt = 64; offt > 0; offt >>= 1) {
        if (tid < offt) {
          float v2 = sval[tid + offt];
          int i2 = sidx[tid + offt];
          if (v2 > sval[tid] || (v2 == sval[tid] && i2 < sidx[tid])) { sval[tid] = v2; sidx[tid] = i2; }
        }
        __syncthreads();
      }
      if (tid == 0) top10_all[bt * 10 + pass] = sidx[0];
      if (tid == sidx[0]) orig[tid] = -__builtin_inff();
      __syncthreads();
    }
  }
}

// ---------------------------------------------------------------------------
// Sequential scan: one workgroup per batch row.
//  - W_hh row per thread in REGISTERS as float4 wr4[25] (100 VGPR; fits the
//    ~168 cap for a 640-thread block -> no scratch spill, unlike R3's 150).
//  - W_ih2 in LDS (120 KB), float2-packed [k2*300+o3]: lane-consecutive o3
//    => 8B stride => 2-way bank aliasing (free).
//  - g2 history in global ws (per-block region); __syncthreads drains vmcnt
//    so intra-block producer->consumer through L1 is safe.
//  - W_query read from global (coalesced, L1-resident after first step).
// LDS ~131 KB -> 1 block/CU (as before).
// ---------------------------------------------------------------------------
__global__ __launch_bounds__(640, 1) void seqk(
    const float* gi1_all, const float* W_hh1, const float* W_hh2, const float* W_ih2,
    const float* b_hh1, const float* b_hh2, const float* b_ih2, const float* b_query,
    const float* wqT, const float* W_W, const float* b_W,
    const float* qw_all, const int* top10_all,
    const float* Eq, const float* Ec, const int* question, const int* cidx, const int* cmask,
    const float* h1_init, const float* h2_init, const float* scal,
    float* g2h, float* out)
{
  const int b = blockIdx.x, tid = threadIdx.x;
  __shared__ float2 wih2s[15000];        // 120 KB: pair (2k2,2k2+1) of W_ih2 row o3 at [k2*300+o3]
  __shared__ float gi1buf[300];
  __shared__ float qc[500];
  __shared__ __align__(16) float h1[100], h2[100], h1n[100], g2v[100], kq[100];
  __shared__ float gh1[300], gh2[300];
  __shared__ float gi2p[2][300];
  __shared__ float kwhist[128];
  __shared__ float ogp[55][2];
  __shared__ float qwl[5];
  __shared__ float pq[5];
  __shared__ int topidx[10];
  __shared__ int qn_s, ci_s[4], cm_s[4];
  __shared__ float kwcur_s;

  // --- W_ih2 -> LDS (one-time) ---
  for (int x = tid; x < 15000; x += 640) {
    int k2 = x / 300, o3 = x % 300;
    wih2s[x] = make_float2(W_ih2[(size_t)o3 * 100 + 2 * k2], W_ih2[(size_t)o3 * 100 + 2 * k2 + 1]);
  }

  // --- W_hh row -> registers (100 VGPR as 25 float4; rows are 400B-aligned) ---
  float4 wr4[25];
  float bh = 0.f, bi2 = 0.f, bqv = 0.f;
  int o3 = 0, half3 = 0;
  if (tid < 600) {
    o3 = tid % 300;
    half3 = tid / 300;
    const float4* src4 = (const float4*)((tid < 300) ? (W_hh1 + (size_t)tid * 100)
                                                     : (W_hh2 + (size_t)(tid - 300) * 100));
#pragma unroll
    for (int k = 0; k < 25; k++) wr4[k] = src4[k];
    bh = (tid < 300) ? b_hh1[tid] : b_hh2[tid - 300];
    if (half3 == 0) bi2 = b_ih2[o3];
  }
  if (tid < 100) bqv = b_query[tid];

  const float bWv = b_W[0];
  const float kw0 = scal[0];
  float* g2hb = g2h + (size_t)b * (T_ * 100);
  if (tid < 100) {
    h1[tid] = h1_init[b * 100 + tid];
    h2[tid] = h2_init[b * 100 + tid];
    g2hb[tid] = 0.f;  // history row 0 stays zero
  }
  if (tid < 128) kwhist[tid] = kw0;
  for (int x = tid; x < 300; x += 640) gi1buf[x] = gi1_all[(size_t)b * T_ * 300 + x];  // t=0 prefetch
  __syncthreads();

  for (int t = 0; t < T_; t++) {
    const size_t bt = (size_t)b * T_ + t;
    // ---- S1: gh1/gh2 matvec from registers; aux loads on tail lanes ----
    if (tid < 600) {
      const float* hsrc = (tid < 300) ? h1 : h2;
      float acc = bh;
#pragma unroll
      for (int k = 0; k < 25; k++) {
        float4 hv = *(const float4*)&hsrc[4 * k];
        float4 w = wr4[k];
        acc += w.x * hv.x + w.y * hv.y + w.z * hv.z + w.w * hv.w;
      }
      if (tid < 300) gh1[tid] = acc;
      else gh2[tid - 300] = acc;
    } else {
      int u = tid - 600;
      if (u < 10) {
        if (t > RK_) {
          int v = top10_all[bt * 10 + u];
          topidx[u] = min(T_ - 1, max(0, v));  // defensive clamp
        }
      } else if (u < 15) {
        qwl[u - 10] = qw_all[bt * 5 + (u - 10)];
      } else if (u == 32) {
        qn_s = question[b * S_ + t + 1];
      }
    }
    __syncthreads();
    // ---- S2: GRU1 combine; concept idx/mask loads ----
    if (tid < 100) {
      int j = tid;
      float r = sigmf(gi1buf[j] + gh1[j]);
      float z = sigmf(gi1buf[100 + j] + gh1[100 + j]);
      float n = tanhf(gi1buf[200 + j] + r * gh1[200 + j]);
      h1n[j] = (1.f - z) * n + z * h1[j];
    } else if (tid >= 104 && tid < 112) {
      int k = tid - 104;
      if (k < 4) ci_s[k] = cidx[qn_s * KC_ + k];
      else cm_s[k - 4] = cmask[qn_s * KC_ + (k - 4)];
    }
    __syncthreads();
    // ---- S3: gi2 partial matvec from LDS weights; qc gather on tail lanes ----
    if (tid < 600) {
      float acc = bi2;
      const float2* wrow = wih2s + half3 * 25 * 300 + o3;
#pragma unroll
      for (int k2 = 0; k2 < 25; k2++) {
        float2 w = wrow[k2 * 300];
        float2 hv = *(const float2*)&h1n[half3 * 50 + 2 * k2];
        acc += w.x * hv.x + w.y * hv.y;
      }
      gi2p[half3][o3] = acc;
    } else {
      for (int x = tid - 600; x < 500; x += 40) {
        int q = x / 100, j = x % 100;
        float v;
        if (q == 0) v = Eq[(size_t)qn_s * 100 + j];
        else v = cm_s[q - 1] ? Ec[(size_t)ci_s[q - 1] * 100 + j] : 0.f;
        qc[x] = v;
      }
    }
    __syncthreads();
    // ---- S4: GRU2 combine ----
    if (tid < 100) {
      int j = tid;
      float gr = gi2p[0][j] + gi2p[1][j];
      float gz = gi2p[0][100 + j] + gi2p[1][100 + j];
      float gn = gi2p[0][200 + j] + gi2p[1][200 + j];
      float r = sigmf(gr + gh2[j]);
      float z = sigmf(gz + gh2[100 + j]);
      float n = tanhf(gn + r * gh2[200 + j]);
      g2v[j] = (1.f - z) * n + z * h2[j];
    }
    __syncthreads();
    // ---- S5: kq matvec | state copies | hist write | og partials | gi1 prefetch ----
    if (tid < 100) {
      int i = tid;
      float acc = bqv;
      for (int j = 0; j < 100; j++) acc += wqT[j * 100 + i] * g2v[j];
      kq[i] = tanhf(acc);
    } else if (tid < 200) {
      h1[tid - 100] = h1n[tid - 100];
    } else if (tid < 300) {
      if (t > 0) h2[tid - 200] = g2v[tid - 200];
    } else if (tid < 400) {
      if (t > 0) g2hb[t * 100 + (tid - 300)] = g2v[tid - 300];
    } else if (tid < 510) {
      int u = tid - 400, d = u >> 1, part = u & 1;
      int s = d / 5, q = d % 5;
      const float* qcr = qc + q * 100;
      float acc = 0.f;
      int jb = part * 50;
      if (s == 0) {
#pragma unroll
        for (int j = 0; j < 50; j += 2) {
          float2 g = *(const float2*)&g2v[jb + j];
          acc += qcr[jb + j] * g.x + qcr[jb + j + 1] * g.y;
        }
      } else {
        int idx = (t > RK_) ? topidx[s - 1] : (s - 1);
        if ((t > RK_) || (s - 1 < t)) {
          const float2* hr = (const float2*)(g2hb + idx * 100 + jb);
          for (int j2 = 0; j2 < 25; j2++) {
            float2 g = hr[j2];
            acc += qcr[jb + 2 * j2] * g.x + qcr[jb + 2 * j2 + 1] * g.y;
          }
        }
      }
      ogp[d][part] = acc;
    } else if (tid >= 576) {
      if (t + 1 < T_) {
        const float* src = gi1_all + (bt + 1) * 300;
        for (int x = tid - 576; x < 300; x += 64) gi1buf[x] = src[x];
      }
    }
    __syncthreads();
    // ---- S6: kw_cur = dot(kq, Wk_part) on wave 8 ----
    if (tid >= 512 && tid < 576) {
      int lane = tid - 512;
      float v = 0.f;
      if (lane < 50) v = kq[lane] * W_W[100 + lane] + kq[lane + 50] * W_W[150 + lane];
      v += __shfl_down(v, 32);
      v += __shfl_down(v, 16);
      v += __shfl_down(v, 8);
      v += __shfl_down(v, 4);
      v += __shfl_down(v, 2);
      v += __shfl_down(v, 1);
      if (lane == 0) kwcur_s = v;
    }
    __syncthreads();
    // ---- S7: per-q softmax over 11 states ----
    if (tid < 5) {
      const int q = tid;
      const float qw = qwl[q];
      float tmp[11];
      float m = -__builtin_inff();
#pragma unroll
      for (int s = 0; s < 11; s++) {
        float kws;
        bool valid;
        if (s == 0) { kws = kwcur_s; valid = true; }
        else if (t > RK_) { kws = kwhist[topidx[s - 1]]; valid = true; }
        else { valid = (s - 1 < t); kws = kwhist[s - 1]; }
        float tv = valid ? (qw + kws + bWv) : NEGV;
        tmp[s] = tv;
        m = fmaxf(m, tv);
      }
      float den = 0.f, num = 0.f;
#pragma unroll
      for (int s = 0; s < 11; s++) {
        float e = expf(tmp[s] - m);
        den += e;
        num += e * (ogp[s * 5 + q][0] + ogp[s * 5 + q][1]);
      }
      pq[q] = num / den;
    } else if (tid == 8) {
      if (t > 0) kwhist[t] = kwcur_s;
    }
    __syncthreads();
    // ---- S8: final sum + store (f32 out) ----
    if (tid == 0) {
      float p = pq[0] + pq[1] + pq[2] + pq[3] + pq[4];
      int col = (t == 0) ? 0 : (t + 1);
      out[b * S_ + col] = p;
      if (t == 0) out[b * S_ + 1] = 0.f;  // col 1 never written by ref (yhat stays 0)
    }
    __syncthreads();
  }
}

// ---------------------------------------------------------------------------
extern "C" void kernel_launch(void* const* d_in, const int* in_sizes, int n_in,
                              void* d_out, int out_size, void* d_ws, size_t ws_size,
                              hipStream_t stream)
{
  (void)in_sizes; (void)n_in; (void)out_size; (void)ws_size;
  const float* Eq     = (const float*)d_in[0];
  const float* Ec     = (const float*)d_in[1];
  const float* Er     = (const float*)d_in[2];
  const float* W_ih1  = (const float*)d_in[3];
  const float* W_hh1  = (const float*)d_in[4];
  const float* b_ih1  = (const float*)d_in[5];
  const float* b_hh1  = (const float*)d_in[6];
  const float* W_ih2  = (const float*)d_in[7];
  const float* W_hh2  = (const float*)d_in[8];
  const float* b_ih2  = (const float*)d_in[9];
  const float* b_hh2  = (const float*)d_in[10];
  const float* Wagg   = (const float*)d_in[11];
  const float* bagg   = (const float*)d_in[12];
  const float* W_last = (const float*)d_in[13];
  const float* b_last = (const float*)d_in[14];
  const float* W_query= (const float*)d_in[15];
  const float* b_query= (const float*)d_in[16];
  const float* W_key  = (const float*)d_in[17];
  const float* b_key  = (const float*)d_in[18];
  const float* W_W    = (const float*)d_in[19];
  const float* b_W    = (const float*)d_in[20];
  const float* h1_init= (const float*)d_in[21];
  const float* h2_init= (const float*)d_in[22];
  const int* question = (const int*)d_in[23];
  const int* response = (const int*)d_in[24];
  const int* mask     = (const int*)d_in[25];
  const int* qnb      = (const int*)d_in[26];
  const int* snb      = (const int*)d_in[27];
  const int* cidx     = (const int*)d_in[28];
  const int* cmask    = (const int*)d_in[29];
  float* out = (float*)d_out;

  char* ws = (char*)d_ws;
  size_t off = 0;
  auto alloc = [&](size_t bytes) -> void* {
    void* p = ws + off;
    off += (bytes + 255) & ~(size_t)255;
    return p;
  };
  float* wih1aT = (float*)alloc(30000 * 4);
  float* erw    = (float*)alloc(600 * 4);
  float* waggT  = (float*)alloc(30000 * 4);
  float* wlastT = (float*)alloc(10000 * 4);
  float* wkeyT  = (float*)alloc(10000 * 4);
  float* wqT    = (float*)alloc(10000 * 4);
  float* scal   = (float*)alloc(4);
  float* gi1_all = (float*)alloc((size_t)B_ * T_ * 300 * 4);
  float* qw_all  = (float*)alloc((size_t)B_ * T_ * 5 * 4);
  int*   top10   = (int*)alloc((size_t)B_ * T_ * 10 * 4);
  float* g2h     = (float*)alloc((size_t)B_ * T_ * 100 * 4);

  hipLaunchKernelGGL(setupk, dim3(128), dim3(256), 0, stream,
      Er, W_ih1, b_ih1, Wagg, W_last, W_key, W_query, b_query, W_W,
      wih1aT, erw, waggT, wlastT, wkeyT, wqT, scal);

  hipLaunchKernelGGL(phaseA, dim3(T_, B_), dim3(256), 0, stream,
      Eq, Ec, question, response, mask, qnb, snb,
      wih1aT, erw, waggT, wlastT, bagg, b_last, gi1_all);

  hipLaunchKernelGGL(phaseB, dim3(T_, B_), dim3(128), 0, stream,
      Eq, Ec, question, cidx, cmask, wkeyT, b_key, W_W,
      qw_all, top10);

  hipLaunchKernelGGL(seqk, dim3(B_), dim3(640), 0, stream,
      gi1_all, W_hh1, W_hh2, W_ih2, b_hh1, b_hh2, b_ih2, b_query,
      wqT, W_W, b_W, qw_all, top10,
      Eq, Ec, question, cidx, cmask,
      h1_init, h2_init, scal, g2h, out);
}